// Round 7
// baseline (161.037 us; speedup 1.0000x reference)
//
#include <hip/hip_runtime.h>

#define B_DIM   2048
#define IN_DIM  4096
#define OUT_DIM 4096
#define FAN     64

// R12: R10's exact structure (best so far: 51.4 us; 8-row 16B cells,
// ds_read_b128, 128 KB double-buffer, 512 thr, launch_bounds(512,1),
// grid (32,8) = 1/CU) + STATIC BANK-GROUP BALANCING of the mask.
//  R11 post-mortem: reloads disproven (VGPR 88, pinned, no gain). Duration
//  == total LDS service time: ~30 cyc per b128 wave-op vs ~12 conflict-free
//  floor. Cause: 64 random 16B cells/op -> bank-group (idx&7) multinomial
//  imbalance (max ~12/8 per group) + counted conflicts.
//  Fix: sum order over f is FREE and the mask is static. reorder_kernel
//  counting-sorts each output's 64 (idx,w) by idx&7 and rotates the stored
//  order by 8*(o&7) (lane class). At step j the 8 lane classes occupy ~8
//  distinct bank groups, ~8 lanes each -> near the 128 B/cyc floor.
//  Branch-free sort: 8 byte-packed counters in a uint64; prefix sums via
//  multiply by 0x0101010101010100 (no runtime-indexed arrays -> no scratch).
//  Workspace: 16 MiB pack + 1 MiB mask2 + 1 MiB weight2 (runtime ws_size
//  check; falls back to original arrays = exact R10 behavior).

typedef float v2f __attribute__((ext_vector_type(2)));

__device__ __forceinline__ unsigned bf16_rne(float f) {
    unsigned u = __float_as_uint(f);
    return (u + 0x7fffu + ((u >> 16) & 1u)) >> 16;   // round-to-nearest-even bf16
}

// ---------------- Phase 0: bank-group-balancing mask reorder ----------------
__global__ __launch_bounds__(256) void reorder_kernel(
    const int* __restrict__ mask, const float* __restrict__ weight,
    int* __restrict__ mask2, float* __restrict__ weight2)
{
    const int o   = blockIdx.x * 256 + threadIdx.x;   // [0, 4096)
    const unsigned rot = 8u * (unsigned)(o & 7);      // lane-class rotation
    const int*   m = mask   + o * FAN;
    const float* w = weight + o * FAN;

    // pass 1: count per bank-group (idx & 7), 8 byte-packed counters
    unsigned long long cnt = 0ull;
    #pragma unroll
    for (int j = 0; j < FAN; ++j)
        cnt += 1ull << (8 * (m[j] & 7));

    // exclusive prefix sums of the 8 byte counters (sums <= 64, no carries)
    unsigned long long off = cnt * 0x0101010101010100ull;

    // pass 2: scatter into sorted-by-group order, rotated by rot
    #pragma unroll
    for (int j = 0; j < FAN; ++j) {
        const int idx = m[j];
        const int g   = idx & 7;
        const unsigned p = (unsigned)(off >> (8 * g)) & 255u;
        off += 1ull << (8 * g);
        const int dst = (int)((p + 64u - rot) & 63u);
        mask2[o * FAN + dst]   = idx;
        weight2[o * FAN + dst] = w[j];
    }
}

// ---------------- Phase 1: pack fp32 -> bf16 8-row cells ----------------
// Tile t = rows 8t..8t+7 (256 tiles); cell (t,c) = 16 B at wsp[t*4096 + c]:
// dw0 = bf16 rows(0,1), dw1 = rows(2,3), dw2 = rows(4,5), dw3 = rows(6,7).
__global__ __launch_bounds__(256) void pack_kernel(
    const float* __restrict__ input, uint4* __restrict__ wsp)
{
    const int idx = blockIdx.x * 256 + threadIdx.x;   // [0, 524288) cell-pairs
    const int t   = idx >> 11;                        // tile [0,256)
    const int c0  = (idx & 2047) << 1;                // column pair base

    const float* p = input + (size_t)t * 8 * IN_DIM + c0;
    float2 r[8];
    #pragma unroll
    for (int i = 0; i < 8; ++i)
        r[i] = *reinterpret_cast<const float2*>(p + i * IN_DIM);

    uint4 q0, q1;                                     // cells c0 and c0+1
    q0.x = bf16_rne(r[0].x) | (bf16_rne(r[1].x) << 16);
    q0.y = bf16_rne(r[2].x) | (bf16_rne(r[3].x) << 16);
    q0.z = bf16_rne(r[4].x) | (bf16_rne(r[5].x) << 16);
    q0.w = bf16_rne(r[6].x) | (bf16_rne(r[7].x) << 16);
    q1.x = bf16_rne(r[0].y) | (bf16_rne(r[1].y) << 16);
    q1.y = bf16_rne(r[2].y) | (bf16_rne(r[3].y) << 16);
    q1.z = bf16_rne(r[4].y) | (bf16_rne(r[5].y) << 16);
    q1.w = bf16_rne(r[6].y) | (bf16_rne(r[7].y) << 16);

    wsp[(size_t)t * 4096 + c0 + 0] = q0;
    wsp[(size_t)t * 4096 + c0 + 1] = q1;
}

// ---------------- Phase 2: pipelined gather + accumulate ----------------
__global__ __launch_bounds__(512, 1) void condensed_kernel(
    const uint4* __restrict__ wsp,
    const float* __restrict__ weight,
    const float* __restrict__ bias,
    const int*   __restrict__ mask,
    float*       __restrict__ out)
{
    __shared__ __align__(16) uint4 lds[8192];         // 128 KB = 2 x 64 KB buffers

    const int tid     = threadIdx.x;
    const int o       = blockIdx.y * 512 + tid;
    const int tbase   = blockIdx.x * 8;               // 8 tiles of 8 rows
    const int rowbase = blockIdx.x * 64;              // 64 batch rows per block

    // ---- idx -> LDS byte addresses (cell = 16 B) + weights, in registers ----
    unsigned addrs[FAN];
    float    wv[FAN];
    {
        const int4*   mv = reinterpret_cast<const int4*>(mask)     + o * (FAN / 4);
        const float4* wp = reinterpret_cast<const float4*>(weight) + o * (FAN / 4);
        #pragma unroll
        for (int j = 0; j < FAN / 4; ++j) {
            int4   m4 = mv[j];
            float4 w4 = wp[j];
            addrs[4*j+0] = (unsigned)m4.x << 4;
            addrs[4*j+1] = (unsigned)m4.y << 4;
            addrs[4*j+2] = (unsigned)m4.z << 4;
            addrs[4*j+3] = (unsigned)m4.w << 4;
            wv[4*j+0] = w4.x;
            wv[4*j+1] = w4.y;
            wv[4*j+2] = w4.z;
            wv[4*j+3] = w4.w;
        }
    }
    const float bv = bias[o];

    // ---- prologue: DMA tile tbase -> buf0 (64 KB = 8 x 16 B per thread) ----
    {
        const uint4* src = wsp + (size_t)tbase * 4096 + tid;
        #pragma unroll
        for (int it = 0; it < 8; ++it) {
            __builtin_amdgcn_global_load_lds(
                (const __attribute__((address_space(1))) unsigned*)(src + it * 512),
                (__attribute__((address_space(3))) unsigned*)(lds + it * 512 + tid),
                16, 0, 0);
        }
    }
    __syncthreads();

    const char* ldsb = reinterpret_cast<const char*>(lds);

    for (int hp = 0; hp < 4; ++hp) {
        // ==== stage A: prefetch tile 2hp+1 -> buf1, compute buf0 (offset 0) ====
        {
            const uint4* src = wsp + (size_t)(tbase + 2 * hp + 1) * 4096 + tid;
            #pragma unroll
            for (int it = 0; it < 8; ++it) {
                __builtin_amdgcn_global_load_lds(
                    (const __attribute__((address_space(1))) unsigned*)(src + it * 512),
                    (__attribute__((address_space(3))) unsigned*)(lds + 4096 + it * 512 + tid),
                    16, 0, 0);
            }
        }
        {
            v2f a01 = {0.f, 0.f}, a23 = {0.f, 0.f}, a45 = {0.f, 0.f}, a67 = {0.f, 0.f};
            #pragma unroll
            for (int j = 0; j < FAN; ++j) {
                const uint4 g = *reinterpret_cast<const uint4*>(ldsb + addrs[j]);
                const v2f w2 = {wv[j], wv[j]};
                v2f v;
                v.x = __uint_as_float(g.x << 16);
                v.y = __uint_as_float(g.x & 0xffff0000u);
                a01 = __builtin_elementwise_fma(v, w2, a01);
                v.x = __uint_as_float(g.y << 16);
                v.y = __uint_as_float(g.y & 0xffff0000u);
                a23 = __builtin_elementwise_fma(v, w2, a23);
                v.x = __uint_as_float(g.z << 16);
                v.y = __uint_as_float(g.z & 0xffff0000u);
                a45 = __builtin_elementwise_fma(v, w2, a45);
                v.x = __uint_as_float(g.w << 16);
                v.y = __uint_as_float(g.w & 0xffff0000u);
                a67 = __builtin_elementwise_fma(v, w2, a67);
            }
            float* op = out + (size_t)(rowbase + 8 * (2 * hp)) * OUT_DIM + o;
            op[0 * OUT_DIM] = a01.x + bv;
            op[1 * OUT_DIM] = a01.y + bv;
            op[2 * OUT_DIM] = a23.x + bv;
            op[3 * OUT_DIM] = a23.y + bv;
            op[4 * OUT_DIM] = a45.x + bv;
            op[5 * OUT_DIM] = a45.y + bv;
            op[6 * OUT_DIM] = a67.x + bv;
            op[7 * OUT_DIM] = a67.y + bv;
        }
        __syncthreads();   // buf0 free; DMA(-> buf1) drained

        // ==== stage B: prefetch tile 2hp+2 -> buf0, compute buf1 (+65536) ====
        if (hp < 3) {
            const uint4* src = wsp + (size_t)(tbase + 2 * hp + 2) * 4096 + tid;
            #pragma unroll
            for (int it = 0; it < 8; ++it) {
                __builtin_amdgcn_global_load_lds(
                    (const __attribute__((address_space(1))) unsigned*)(src + it * 512),
                    (__attribute__((address_space(3))) unsigned*)(lds + it * 512 + tid),
                    16, 0, 0);
            }
        }
        {
            v2f a01 = {0.f, 0.f}, a23 = {0.f, 0.f}, a45 = {0.f, 0.f}, a67 = {0.f, 0.f};
            #pragma unroll
            for (int j = 0; j < FAN; ++j) {
                // +65536 = buf1; one v_add per read (doesn't fit offset field)
                const uint4 g = *reinterpret_cast<const uint4*>(ldsb + 65536 + addrs[j]);
                const v2f w2 = {wv[j], wv[j]};
                v2f v;
                v.x = __uint_as_float(g.x << 16);
                v.y = __uint_as_float(g.x & 0xffff0000u);
                a01 = __builtin_elementwise_fma(v, w2, a01);
                v.x = __uint_as_float(g.y << 16);
                v.y = __uint_as_float(g.y & 0xffff0000u);
                a23 = __builtin_elementwise_fma(v, w2, a23);
                v.x = __uint_as_float(g.z << 16);
                v.y = __uint_as_float(g.z & 0xffff0000u);
                a45 = __builtin_elementwise_fma(v, w2, a45);
                v.x = __uint_as_float(g.w << 16);
                v.y = __uint_as_float(g.w & 0xffff0000u);
                a67 = __builtin_elementwise_fma(v, w2, a67);
            }
            float* op = out + (size_t)(rowbase + 8 * (2 * hp + 1)) * OUT_DIM + o;
            op[0 * OUT_DIM] = a01.x + bv;
            op[1 * OUT_DIM] = a01.y + bv;
            op[2 * OUT_DIM] = a23.x + bv;
            op[3 * OUT_DIM] = a23.y + bv;
            op[4 * OUT_DIM] = a45.x + bv;
            op[5 * OUT_DIM] = a45.y + bv;
            op[6 * OUT_DIM] = a67.x + bv;
            op[7 * OUT_DIM] = a67.y + bv;
        }
        __syncthreads();   // buf1 free; DMA(-> buf0) drained
    }
}

extern "C" void kernel_launch(void* const* d_in, const int* in_sizes, int n_in,
                              void* d_out, int out_size, void* d_ws, size_t ws_size,
                              hipStream_t stream) {
    const float* input  = (const float*)d_in[0];
    const float* weight = (const float*)d_in[1];
    const float* bias   = (const float*)d_in[2];
    const int*   mask   = (const int*)d_in[3];
    float*       out    = (float*)d_out;
    uint4*       wsp    = (uint4*)d_ws;               // 16 MiB pack region

    const size_t pack_bytes = (size_t)16 * 1024 * 1024;
    const size_t m2_bytes   = (size_t)OUT_DIM * FAN * sizeof(int);    // 1 MiB
    const size_t w2_bytes   = (size_t)OUT_DIM * FAN * sizeof(float);  // 1 MiB

    const int* use_m = mask;
    const float* use_w = weight;
    if (ws_size >= pack_bytes + m2_bytes + w2_bytes) {
        int*   mask2   = (int*)((char*)d_ws + pack_bytes);
        float* weight2 = (float*)((char*)d_ws + pack_bytes + m2_bytes);
        reorder_kernel<<<16, 256, 0, stream>>>(mask, weight, mask2, weight2);
        use_m = mask2;
        use_w = weight2;
    }

    pack_kernel<<<2048, 256, 0, stream>>>(input, wsp);
    dim3 grid(32, 8);   // 256 blocks = exactly 1/CU (128 KB LDS, 512 threads)
    condensed_kernel<<<grid, 512, 0, stream>>>(wsp, use_w, bias, use_m, out);
}